// Round 4
// baseline (2748.846 us; speedup 1.0000x reference)
//
#include <hip/hip_runtime.h>

#define LF 8192
#define NB 8
#define NC 512
#define NA 7
#define NANCH 57344        // LF*NA
#define PRE_K 600
#define POST_K 100

// output layout (floats), concatenated in reference return order
#define OBJ_OFF   0
#define REG_OFF   458752
#define ANCH_OFF  1376256
#define PROPS_OFF 1490944
#define PSC_OFF   1492544
#define PM_OFF    1493344

// ---------------- weight transpose: conv_w[co][ci][k] -> wt[(ci*3+k)*512+co] ----
__global__ void transpose_w_k(const float* __restrict__ cw, float* __restrict__ wt) {
  int o = blockIdx.x * 256 + threadIdx.x;
  if (o >= 512 * 512 * 3) return;
  int co = o & 511;
  int r  = o >> 9;            // ci*3 + k
  int ci = r / 3;
  int k  = r - ci * 3;
  wt[o] = cw[((size_t)co * 512 + ci) * 3 + k];
}

// ---------------- anchors ------------------------------------------------------
__global__ void anchors_k(float* __restrict__ out) {
  int i = blockIdx.x * 256 + threadIdx.x;
  if (i >= NANCH) return;
  int l = i / 7, a = i - l * 7;
  float len = (float)(a + 1 + (a > 4 ? a - 4 : 0));   // {1,2,3,4,5,7,9}
  float c = (float)l + 0.5f;
  out[ANCH_OFF + 2 * (size_t)i]     = c - 0.5f * len;
  out[ANCH_OFF + 2 * (size_t)i + 1] = c + 0.5f * len;
}

// ---------------- fused conv1d + ReLU + obj/reg projection ---------------------
// lane = c_out, l-tile of 32 in registers. grid (LF/32, B), block 256.
// Thread t owns c_out {t, t+256}; acc0/acc1[32] live in VGPRs.
// __launch_bounds__ second arg MUST be 2: arg=4 imposes a 64-VGPR cap on this
// toolchain (R2/R3: VGPR_Count==64 + 2.2 GB scratch spill; R1 with arg=2: 68
// VGPRs, zero spill).
__global__ __launch_bounds__(256, 2) void conv_proj_k(
    const float* __restrict__ feat, const float* __restrict__ wt,
    const float* __restrict__ cbias, const float* __restrict__ obj_w,
    const float* __restrict__ obj_b, const float* __restrict__ reg_w,
    const float* __restrict__ reg_b, float* __restrict__ out)
{
  __shared__ float sf[32][36];      // feat chunk [ci][l0-1 .. l0+32]
  __shared__ float bufp[128][33];   // h quarter [co_local][l], odd stride -> conflict-free
  const int tid = threadIdx.x;
  const int l0  = blockIdx.x * 32;
  const int b   = blockIdx.y;
  const int co0 = tid;
  const int co1 = tid + 256;

  float acc0[32], acc1[32];
  {
    float b0 = cbias[co0], b1 = cbias[co1];
    #pragma unroll
    for (int j = 0; j < 32; ++j) { acc0[j] = b0; acc1[j] = b1; }
  }

  const float* fb = feat + ((size_t)b * 512) * LF;

  for (int cb = 0; cb < 512; cb += 32) {
    __syncthreads();
    #pragma unroll
    for (int t = 0; t < 5; ++t) {            // 32*34 = 1088 elements
      int idx = tid + t * 256;
      if (idx < 1088) {
        int r = idx / 34, c = idx - r * 34;
        int gl = l0 - 1 + c;
        float v = 0.f;
        if (gl >= 0 && gl < LF) v = fb[(size_t)(cb + r) * LF + gl];
        sf[r][c] = v;
      }
    }
    __syncthreads();
    for (int ci = 0; ci < 32; ++ci) {
      const float* wp = wt + (size_t)(cb + ci) * 1536;
      float w00 = wp[co0], w01 = wp[512 + co0], w02 = wp[1024 + co0];
      float w10 = wp[co1], w11 = wp[512 + co1], w12 = wp[1024 + co1];
      const float4* fr = (const float4*)&sf[ci][0];   // wave-uniform -> broadcast
      float4 cur = fr[0];
      #pragma unroll
      for (int g = 0; g < 8; ++g) {
        float4 nxt = fr[g + 1];
        int l = 4 * g;
        acc0[l]     = fmaf(w00, cur.x, fmaf(w01, cur.y, fmaf(w02, cur.z, acc0[l])));
        acc1[l]     = fmaf(w10, cur.x, fmaf(w11, cur.y, fmaf(w12, cur.z, acc1[l])));
        acc0[l + 1] = fmaf(w00, cur.y, fmaf(w01, cur.z, fmaf(w02, cur.w, acc0[l + 1])));
        acc1[l + 1] = fmaf(w10, cur.y, fmaf(w11, cur.z, fmaf(w12, cur.w, acc1[l + 1])));
        acc0[l + 2] = fmaf(w00, cur.z, fmaf(w01, cur.w, fmaf(w02, nxt.x, acc0[l + 2])));
        acc1[l + 2] = fmaf(w10, cur.z, fmaf(w11, cur.w, fmaf(w12, nxt.x, acc1[l + 2])));
        acc0[l + 3] = fmaf(w00, cur.w, fmaf(w01, nxt.x, fmaf(w02, nxt.y, acc0[l + 3])));
        acc1[l + 3] = fmaf(w10, cur.w, fmaf(w11, nxt.x, fmaf(w12, nxt.y, acc1[l + 3])));
        cur = nxt;
      }
    }
  }

  // ---- projection epilogue: route h through LDS in 128-co quarters ----
  const int sg = tid >> 5;          // subgroup 0..7: rows r = 3*sg + q
  const int ll = tid & 31;          // l within tile
  const int r0 = sg * 3;
  int rc0 = r0     < 21 ? r0     : 20;
  int rc1 = r0 + 1 < 21 ? r0 + 1 : 20;
  int rc2 = r0 + 2 < 21 ? r0 + 2 : 20;
  const float* wr0 = (rc0 < 7) ? (obj_w + (size_t)rc0 * 512) : (reg_w + (size_t)(rc0 - 7) * 512);
  const float* wr1 = (rc1 < 7) ? (obj_w + (size_t)rc1 * 512) : (reg_w + (size_t)(rc1 - 7) * 512);
  const float* wr2 = (rc2 < 7) ? (obj_w + (size_t)rc2 * 512) : (reg_w + (size_t)(rc2 - 7) * 512);
  float pacc0 = 0.f, pacc1 = 0.f, pacc2 = 0.f;

  #pragma unroll
  for (int qh = 0; qh < 4; ++qh) {
    __syncthreads();
    if (qh == 0) {
      if (tid < 128) {
        #pragma unroll
        for (int j = 0; j < 32; ++j) bufp[tid][j] = fmaxf(acc0[j], 0.f);
      }
    } else if (qh == 1) {
      if (tid >= 128) {
        #pragma unroll
        for (int j = 0; j < 32; ++j) bufp[tid - 128][j] = fmaxf(acc0[j], 0.f);
      }
    } else if (qh == 2) {
      if (tid < 128) {
        #pragma unroll
        for (int j = 0; j < 32; ++j) bufp[tid][j] = fmaxf(acc1[j], 0.f);
      }
    } else {
      if (tid >= 128) {
        #pragma unroll
        for (int j = 0; j < 32; ++j) bufp[tid - 128][j] = fmaxf(acc1[j], 0.f);
      }
    }
    __syncthreads();
    const float* w0p = wr0 + qh * 128;
    const float* w1p = wr1 + qh * 128;
    const float* w2p = wr2 + qh * 128;
    for (int c4 = 0; c4 < 32; ++c4) {
      float4 wa = *(const float4*)(w0p + 4 * c4);
      float4 wb = *(const float4*)(w1p + 4 * c4);
      float4 wc = *(const float4*)(w2p + 4 * c4);
      float h0 = bufp[4 * c4 + 0][ll];
      float h1 = bufp[4 * c4 + 1][ll];
      float h2 = bufp[4 * c4 + 2][ll];
      float h3 = bufp[4 * c4 + 3][ll];
      pacc0 = fmaf(wa.x, h0, fmaf(wa.y, h1, fmaf(wa.z, h2, fmaf(wa.w, h3, pacc0))));
      pacc1 = fmaf(wb.x, h0, fmaf(wb.y, h1, fmaf(wb.z, h2, fmaf(wb.w, h3, pacc1))));
      pacc2 = fmaf(wc.x, h0, fmaf(wc.y, h1, fmaf(wc.z, h2, fmaf(wc.w, h3, pacc2))));
    }
  }

  const size_t ob = (size_t)b * NANCH;
  const int l = l0 + ll;
  {
    int r = r0;
    if (r < 21) {
      float v = pacc0 + ((r < 7) ? obj_b[r] : reg_b[r - 7]);
      if (r < 7) out[OBJ_OFF + ob + (size_t)l * 7 + r] = v;
      else { int rr = r - 7; out[REG_OFF + (ob + (size_t)l * 7 + (rr >> 1)) * 2 + (rr & 1)] = v; }
    }
    r = r0 + 1;
    if (r < 21) {
      float v = pacc1 + ((r < 7) ? obj_b[r] : reg_b[r - 7]);
      if (r < 7) out[OBJ_OFF + ob + (size_t)l * 7 + r] = v;
      else { int rr = r - 7; out[REG_OFF + (ob + (size_t)l * 7 + (rr >> 1)) * 2 + (rr & 1)] = v; }
    }
    r = r0 + 2;
    if (r < 21) {
      float v = pacc2 + ((r < 7) ? obj_b[r] : reg_b[r - 7]);
      if (r < 7) out[OBJ_OFF + ob + (size_t)l * 7 + r] = v;
      else { int rr = r - 7; out[REG_OFF + (ob + (size_t)l * 7 + (rr >> 1)) * 2 + (rr & 1)] = v; }
    }
  }
}

// ---------------- helper: locate bin containing rank-K from top ----------------
__device__ __forceinline__ void find_bin(unsigned* hist, unsigned* coarse,
                                         int K, int tid, int* res) {
  unsigned s4 = hist[4 * tid] + hist[4 * tid + 1] + hist[4 * tid + 2] + hist[4 * tid + 3];
  coarse[tid] = s4;
  __syncthreads();
  for (int off = 1; off < 256; off <<= 1) {
    unsigned v = coarse[tid];
    unsigned add = (tid + off < 256) ? coarse[tid + off] : 0u;
    __syncthreads();
    coarse[tid] = v + add;
    __syncthreads();
  }
  unsigned sfx  = coarse[tid];
  unsigned sfx1 = (tid < 255) ? coarse[tid + 1] : 0u;
  if (sfx >= (unsigned)K && sfx1 < (unsigned)K) {
    unsigned above = sfx1;
    int bin = 4 * tid;
    for (int bb = 4 * tid + 3; bb >= 4 * tid; --bb) {
      unsigned c = hist[bb];
      if (above + c >= (unsigned)K) { bin = bb; break; }
      above += c;
    }
    res[0] = bin;
    res[1] = (int)above;
  }
  __syncthreads();
}

// monotone sortable bits of a float logit (total order == value order)
__device__ __forceinline__ unsigned keybits(float x) {
  unsigned u = __float_as_uint(x);
  return (u & 0x80000000u) ? ~u : (u | 0x80000000u);
}

// ---------------- per-batch top-600 -> NMS -> top-100 --------------------------
__global__ __launch_bounds__(256) void propose_k(float* __restrict__ out) {
  const int b = blockIdx.x;
  const int tid = threadIdx.x;
  const int lane = tid & 63;
  const int wave = tid >> 6;

  __shared__ unsigned long long pool[PRE_K * 10];  // 48 KB; first 1024 = sort keys
  __shared__ unsigned int hist[1024];
  __shared__ unsigned int coarse[256];
  __shared__ float bs[PRE_K], be[PRE_K], bsc[PRE_K];
  __shared__ unsigned long long vwords[10];
  __shared__ int scal[4];   // 0: bin, 1: before, 2: cand cnt, 3: kept

  unsigned long long* keys = pool;
  const float* obj = out + OBJ_OFF + (size_t)b * NANCH;

  for (int i = tid; i < 1024; i += 256) hist[i] = 0u;
  if (tid < 10) vwords[tid] = 0ull;
  if (tid == 0) scal[2] = 0;
  __syncthreads();

  // pass 1: histogram on sortable logit bits [31:22]
  for (int i = tid; i < NANCH; i += 256) {
    unsigned u = keybits(obj[i]);
    atomicAdd(&hist[u >> 22], 1u);
  }
  __syncthreads();
  find_bin(hist, coarse, PRE_K, tid, scal);
  const int b1 = scal[0];
  const int before = scal[1];
  __syncthreads();
  for (int i = tid; i < 1024; i += 256) hist[i] = 0u;
  __syncthreads();
  // pass 2: refine next 10 bits within bin b1
  for (int i = tid; i < NANCH; i += 256) {
    unsigned u = keybits(obj[i]);
    if ((int)(u >> 22) == b1) atomicAdd(&hist[(u >> 12) & 1023u], 1u);
  }
  __syncthreads();
  find_bin(hist, coarse, PRE_K - before, tid, scal);
  const unsigned Tbits = ((unsigned)b1 << 22) | ((unsigned)scal[0] << 12);
  __syncthreads();
  // gather candidates (>=600 guaranteed, ~600 expected)
  for (int i = tid; i < NANCH; i += 256) {
    unsigned u = keybits(obj[i]);
    if (u >= Tbits) {
      int p = atomicAdd(&scal[2], 1);
      if (p < 1024)
        keys[p] = ((unsigned long long)u << 32) | (unsigned long long)(~(unsigned)i);
    }
  }
  __syncthreads();
  const int cnt = scal[2];
  for (int p = tid; p < 1024; p += 256) if (p >= cnt) keys[p] = 0ull;
  // bitonic sort descending (key: logit bits major, ~idx minor -> ties by lower idx)
  for (unsigned k = 2; k <= 1024; k <<= 1) {
    for (unsigned j = k >> 1; j > 0; j >>= 1) {
      __syncthreads();
      for (unsigned idx = tid; idx < 1024; idx += 256) {
        unsigned partner = idx ^ j;
        if (partner > idx) {
          unsigned long long a = keys[idx], c = keys[partner];
          bool up = ((idx & k) == 0);
          if (up ? (a < c) : (a > c)) { keys[idx] = c; keys[partner] = a; }
        }
      }
    }
  }
  __syncthreads();
  // decode top-600 boxes
  for (int t = tid; t < PRE_K; t += 256) {
    unsigned long long kv = keys[t];
    unsigned u  = (unsigned)(kv >> 32);
    unsigned i2 = ~((unsigned)kv);
    unsigned ub = (u & 0x80000000u) ? (u & 0x7fffffffu) : ~u;
    float logit = __uint_as_float(ub);
    float score = 1.f / (1.f + expf(-logit));
    int li = (int)(i2 / 7u);
    int a  = (int)(i2 - (unsigned)li * 7u);
    float alen = (float)(a + 1 + (a > 4 ? a - 4 : 0));
    const float* rp = out + REG_OFF + ((size_t)b * NANCH + i2) * 2;
    float tc = rp[0];
    float tw = fminf(fmaxf(rp[1], -10.f), 10.f);
    float cc = (float)li + 0.5f + tc * alen;
    float ww = alen * expf(tw);
    float s0 = cc - 0.5f * ww;
    float e0 = cc + 0.5f * ww;
    s0 = fminf(fmaxf(s0, 0.f), (float)LF);
    e0 = fminf(fmaxf(e0, 0.f), (float)LF);
    e0 = fminf(fmaxf(e0, s0 + 1e-3f), (float)LF);
    s0 = fmaxf(fminf(s0, e0 - 1e-3f), 0.f);
    bs[t] = s0; be[t] = e0; bsc[t] = score;
    if (score >= 0.1f) atomicOr(&vwords[t >> 6], 1ull << (t & 63));
  }
  __syncthreads();
  // suppression masks: pool[j*10+w] = bits i>j with iou(i,j) > 0.5
  for (int widx = tid; widx < PRE_K * 10; widx += 256) {
    int j = widx / 10;
    int w = widx - j * 10;
    int base = w * 64;
    unsigned long long m = 0ull;
    if (base + 63 > j) {
      float sj = bs[j], ej = be[j];
      float wj = ej - sj;
      for (int bit = 0; bit < 64; ++bit) {
        int i3 = base + bit;
        if (i3 > j && i3 < PRE_K) {
          float inter = fmaxf(fminf(ej, be[i3]) - fmaxf(sj, bs[i3]), 0.f);
          float uni = wj + (be[i3] - bs[i3]) - inter;
          float iou = inter / fmaxf(uni, 1e-6f);
          if (iou > 0.5f) m |= (1ull << bit);
        }
      }
    }
    pool[widx] = m;
  }
  __syncthreads();
  // wave-serial greedy NMS + output (lane w<10 owns removal word w)
  if (wave == 0) {
    unsigned long long rem = 0ull;
    unsigned long long vw = (lane < 10) ? vwords[lane] : 0ull;
    unsigned long long mrow = (lane < 10) ? pool[lane] : 0ull;
    int kept = 0;
    for (int i3 = 0; i3 < PRE_K; ++i3) {
      unsigned long long mnext =
          (lane < 10 && (i3 + 1) < PRE_K) ? pool[(i3 + 1) * 10 + lane] : 0ull;
      unsigned long long avail = vw & ~rem;
      unsigned long long ow = __shfl(avail, i3 >> 6);
      if ((ow >> (i3 & 63)) & 1ull) {
        rem |= mrow;
        if (lane == 0) {
          out[PROPS_OFF + (size_t)b * 200 + 2 * kept]     = bs[i3];
          out[PROPS_OFF + (size_t)b * 200 + 2 * kept + 1] = be[i3];
          out[PSC_OFF + (size_t)b * 100 + kept] = bsc[i3];
          out[PM_OFF  + (size_t)b * 100 + kept] = 1.0f;
        }
        ++kept;
        if (kept >= POST_K) break;
      }
      mrow = mnext;
    }
    if (lane == 0) scal[3] = kept;
  }
  __syncthreads();
  const int kf = scal[3];
  for (int r = tid; r < POST_K; r += 256) {
    if (r >= kf) {
      out[PROPS_OFF + (size_t)b * 200 + 2 * r]     = 0.f;
      out[PROPS_OFF + (size_t)b * 200 + 2 * r + 1] = 0.f;
      out[PSC_OFF + (size_t)b * 100 + r] = 0.f;
      out[PM_OFF  + (size_t)b * 100 + r] = 0.f;
    }
  }
}

extern "C" void kernel_launch(void* const* d_in, const int* in_sizes, int n_in,
                              void* d_out, int out_size, void* d_ws, size_t ws_size,
                              hipStream_t stream) {
  const float* feat = (const float*)d_in[0];
  const float* cw   = (const float*)d_in[1];
  const float* cb   = (const float*)d_in[2];
  const float* ow   = (const float*)d_in[3];
  const float* obb  = (const float*)d_in[4];
  const float* rw   = (const float*)d_in[5];
  const float* rb   = (const float*)d_in[6];
  float* out = (float*)d_out;
  float* wt  = (float*)d_ws;   // 3 MB transposed conv weights

  hipLaunchKernelGGL(transpose_w_k, dim3(3072), dim3(256), 0, stream, cw, wt);
  hipLaunchKernelGGL(anchors_k, dim3(224), dim3(256), 0, stream, out);
  hipLaunchKernelGGL(conv_proj_k, dim3(256, 8), dim3(256), 0, stream,
                     feat, wt, cb, ow, obb, rw, rb, out);
  hipLaunchKernelGGL(propose_k, dim3(8), dim3(256), 0, stream, out);
}

// Round 5
// 2547.554 us; speedup vs baseline: 1.0790x; 1.0790x over previous
//
#include <hip/hip_runtime.h>

#define LF 8192
#define NB 8
#define NC 512
#define NA 7
#define NANCH 57344        // LF*NA
#define PRE_K 600
#define POST_K 100

// output layout (floats), concatenated in reference return order
#define OBJ_OFF   0
#define REG_OFF   458752
#define ANCH_OFF  1376256
#define PROPS_OFF 1490944
#define PSC_OFF   1492544
#define PM_OFF    1493344

// ---------------- weight transpose: conv_w[co][ci][k] -> wt[(ci*3+k)*512+co] ----
__global__ void transpose_w_k(const float* __restrict__ cw, float* __restrict__ wt) {
  int o = blockIdx.x * 256 + threadIdx.x;
  if (o >= 512 * 512 * 3) return;
  int co = o & 511;
  int r  = o >> 9;            // ci*3 + k
  int ci = r / 3;
  int k  = r - ci * 3;
  wt[o] = cw[((size_t)co * 512 + ci) * 3 + k];
}

// ---------------- anchors ------------------------------------------------------
__global__ void anchors_k(float* __restrict__ out) {
  int i = blockIdx.x * 256 + threadIdx.x;
  if (i >= NANCH) return;
  int l = i / 7, a = i - l * 7;
  float len = (float)(a + 1 + (a > 4 ? a - 4 : 0));   // {1,2,3,4,5,7,9}
  float c = (float)l + 0.5f;
  out[ANCH_OFF + 2 * (size_t)i]     = c - 0.5f * len;
  out[ANCH_OFF + 2 * (size_t)i + 1] = c + 0.5f * len;
}

// ---------------- fused conv1d + ReLU + obj/reg projection ---------------------
// lane = c_out, l-tile of 32 in registers. grid (LF/32, B), block 256.
// Thread t owns c_out {t, t+256}; acc0/acc1[32] live in VGPRs.
// MEASURED CAP LAW (R1/R3/R4): __launch_bounds__(256, w) caps VGPRs at 256/w.
// w=4 -> 64 cap, w=2 -> 128 cap; this kernel needs ~135-160, so ANY second
// arg >=2 forces whole-accumulator spill (~2 GB scratch traffic). Use plain
// __launch_bounds__(256): cap 256, allocator free.
__global__ __launch_bounds__(256) void conv_proj_k(
    const float* __restrict__ feat, const float* __restrict__ wt,
    const float* __restrict__ cbias, const float* __restrict__ obj_w,
    const float* __restrict__ obj_b, const float* __restrict__ reg_w,
    const float* __restrict__ reg_b, float* __restrict__ out)
{
  __shared__ float sf[32][36];      // feat chunk [ci][l0-1 .. l0+32]
  __shared__ float bufp[128][33];   // h quarter [co_local][l], odd stride -> conflict-free
  const int tid = threadIdx.x;
  const int l0  = blockIdx.x * 32;
  const int b   = blockIdx.y;
  const int co0 = tid;
  const int co1 = tid + 256;

  float acc0[32], acc1[32];
  {
    float b0 = cbias[co0], b1 = cbias[co1];
    #pragma unroll
    for (int j = 0; j < 32; ++j) { acc0[j] = b0; acc1[j] = b1; }
  }

  const float* fb = feat + ((size_t)b * 512) * LF;

  for (int cb = 0; cb < 512; cb += 32) {
    __syncthreads();
    #pragma unroll
    for (int t = 0; t < 5; ++t) {            // 32*34 = 1088 elements
      int idx = tid + t * 256;
      if (idx < 1088) {
        int r = idx / 34, c = idx - r * 34;
        int gl = l0 - 1 + c;
        float v = 0.f;
        if (gl >= 0 && gl < LF) v = fb[(size_t)(cb + r) * LF + gl];
        sf[r][c] = v;
      }
    }
    __syncthreads();
    for (int ci = 0; ci < 32; ++ci) {
      const float* wp = wt + (size_t)(cb + ci) * 1536;
      float w00 = wp[co0], w01 = wp[512 + co0], w02 = wp[1024 + co0];
      float w10 = wp[co1], w11 = wp[512 + co1], w12 = wp[1024 + co1];
      const float4* fr = (const float4*)&sf[ci][0];   // wave-uniform -> broadcast
      float4 cur = fr[0];
      #pragma unroll
      for (int g = 0; g < 8; ++g) {
        float4 nxt = fr[g + 1];
        int l = 4 * g;
        acc0[l]     = fmaf(w00, cur.x, fmaf(w01, cur.y, fmaf(w02, cur.z, acc0[l])));
        acc1[l]     = fmaf(w10, cur.x, fmaf(w11, cur.y, fmaf(w12, cur.z, acc1[l])));
        acc0[l + 1] = fmaf(w00, cur.y, fmaf(w01, cur.z, fmaf(w02, cur.w, acc0[l + 1])));
        acc1[l + 1] = fmaf(w10, cur.y, fmaf(w11, cur.z, fmaf(w12, cur.w, acc1[l + 1])));
        acc0[l + 2] = fmaf(w00, cur.z, fmaf(w01, cur.w, fmaf(w02, nxt.x, acc0[l + 2])));
        acc1[l + 2] = fmaf(w10, cur.z, fmaf(w11, cur.w, fmaf(w12, nxt.x, acc1[l + 2])));
        acc0[l + 3] = fmaf(w00, cur.w, fmaf(w01, nxt.x, fmaf(w02, nxt.y, acc0[l + 3])));
        acc1[l + 3] = fmaf(w10, cur.w, fmaf(w11, nxt.x, fmaf(w12, nxt.y, acc1[l + 3])));
        cur = nxt;
      }
    }
  }

  // ---- projection epilogue: route h through LDS in 128-co quarters ----
  // scalar (non-float4) weight loads: keeps epilogue peak pressure ~36 regs
  // lower; epilogue is ~2% of runtime so load width is irrelevant here.
  const int sg = tid >> 5;          // subgroup 0..7: rows r = 3*sg + q
  const int ll = tid & 31;          // l within tile
  const int r0 = sg * 3;
  int rc0 = r0     < 21 ? r0     : 20;
  int rc1 = r0 + 1 < 21 ? r0 + 1 : 20;
  int rc2 = r0 + 2 < 21 ? r0 + 2 : 20;
  const float* wr0 = (rc0 < 7) ? (obj_w + (size_t)rc0 * 512) : (reg_w + (size_t)(rc0 - 7) * 512);
  const float* wr1 = (rc1 < 7) ? (obj_w + (size_t)rc1 * 512) : (reg_w + (size_t)(rc1 - 7) * 512);
  const float* wr2 = (rc2 < 7) ? (obj_w + (size_t)rc2 * 512) : (reg_w + (size_t)(rc2 - 7) * 512);
  float pacc0 = 0.f, pacc1 = 0.f, pacc2 = 0.f;

  #pragma unroll
  for (int qh = 0; qh < 4; ++qh) {
    __syncthreads();
    if (qh == 0) {
      if (tid < 128) {
        #pragma unroll
        for (int j = 0; j < 32; ++j) bufp[tid][j] = fmaxf(acc0[j], 0.f);
      }
    } else if (qh == 1) {
      if (tid >= 128) {
        #pragma unroll
        for (int j = 0; j < 32; ++j) bufp[tid - 128][j] = fmaxf(acc0[j], 0.f);
      }
    } else if (qh == 2) {
      if (tid < 128) {
        #pragma unroll
        for (int j = 0; j < 32; ++j) bufp[tid][j] = fmaxf(acc1[j], 0.f);
      }
    } else {
      if (tid >= 128) {
        #pragma unroll
        for (int j = 0; j < 32; ++j) bufp[tid - 128][j] = fmaxf(acc1[j], 0.f);
      }
    }
    __syncthreads();
    const float* w0p = wr0 + qh * 128;
    const float* w1p = wr1 + qh * 128;
    const float* w2p = wr2 + qh * 128;
    for (int c = 0; c < 128; ++c) {
      float wa = w0p[c];
      float wb = w1p[c];
      float wc = w2p[c];
      float hv = bufp[c][ll];
      pacc0 = fmaf(wa, hv, pacc0);
      pacc1 = fmaf(wb, hv, pacc1);
      pacc2 = fmaf(wc, hv, pacc2);
    }
  }

  const size_t ob = (size_t)b * NANCH;
  const int l = l0 + ll;
  {
    int r = r0;
    if (r < 21) {
      float v = pacc0 + ((r < 7) ? obj_b[r] : reg_b[r - 7]);
      if (r < 7) out[OBJ_OFF + ob + (size_t)l * 7 + r] = v;
      else { int rr = r - 7; out[REG_OFF + (ob + (size_t)l * 7 + (rr >> 1)) * 2 + (rr & 1)] = v; }
    }
    r = r0 + 1;
    if (r < 21) {
      float v = pacc1 + ((r < 7) ? obj_b[r] : reg_b[r - 7]);
      if (r < 7) out[OBJ_OFF + ob + (size_t)l * 7 + r] = v;
      else { int rr = r - 7; out[REG_OFF + (ob + (size_t)l * 7 + (rr >> 1)) * 2 + (rr & 1)] = v; }
    }
    r = r0 + 2;
    if (r < 21) {
      float v = pacc2 + ((r < 7) ? obj_b[r] : reg_b[r - 7]);
      if (r < 7) out[OBJ_OFF + ob + (size_t)l * 7 + r] = v;
      else { int rr = r - 7; out[REG_OFF + (ob + (size_t)l * 7 + (rr >> 1)) * 2 + (rr & 1)] = v; }
    }
  }
}

// ---------------- helper: locate bin containing rank-K from top ----------------
__device__ __forceinline__ void find_bin(unsigned* hist, unsigned* coarse,
                                         int K, int tid, int* res) {
  unsigned s4 = hist[4 * tid] + hist[4 * tid + 1] + hist[4 * tid + 2] + hist[4 * tid + 3];
  coarse[tid] = s4;
  __syncthreads();
  for (int off = 1; off < 256; off <<= 1) {
    unsigned v = coarse[tid];
    unsigned add = (tid + off < 256) ? coarse[tid + off] : 0u;
    __syncthreads();
    coarse[tid] = v + add;
    __syncthreads();
  }
  unsigned sfx  = coarse[tid];
  unsigned sfx1 = (tid < 255) ? coarse[tid + 1] : 0u;
  if (sfx >= (unsigned)K && sfx1 < (unsigned)K) {
    unsigned above = sfx1;
    int bin = 4 * tid;
    for (int bb = 4 * tid + 3; bb >= 4 * tid; --bb) {
      unsigned c = hist[bb];
      if (above + c >= (unsigned)K) { bin = bb; break; }
      above += c;
    }
    res[0] = bin;
    res[1] = (int)above;
  }
  __syncthreads();
}

// monotone sortable bits of a float logit (total order == value order)
__device__ __forceinline__ unsigned keybits(float x) {
  unsigned u = __float_as_uint(x);
  return (u & 0x80000000u) ? ~u : (u | 0x80000000u);
}

// ---------------- per-batch top-600 -> NMS -> top-100 --------------------------
__global__ __launch_bounds__(256) void propose_k(float* __restrict__ out) {
  const int b = blockIdx.x;
  const int tid = threadIdx.x;
  const int lane = tid & 63;
  const int wave = tid >> 6;

  __shared__ unsigned long long pool[PRE_K * 10];  // 48 KB; first 1024 = sort keys
  __shared__ unsigned int hist[1024];
  __shared__ unsigned int coarse[256];
  __shared__ float bs[PRE_K], be[PRE_K], bsc[PRE_K];
  __shared__ unsigned long long vwords[10];
  __shared__ int scal[4];   // 0: bin, 1: before, 2: cand cnt, 3: kept

  unsigned long long* keys = pool;
  const float* obj = out + OBJ_OFF + (size_t)b * NANCH;

  for (int i = tid; i < 1024; i += 256) hist[i] = 0u;
  if (tid < 10) vwords[tid] = 0ull;
  if (tid == 0) scal[2] = 0;
  __syncthreads();

  // pass 1: histogram on sortable logit bits [31:22]
  for (int i = tid; i < NANCH; i += 256) {
    unsigned u = keybits(obj[i]);
    atomicAdd(&hist[u >> 22], 1u);
  }
  __syncthreads();
  find_bin(hist, coarse, PRE_K, tid, scal);
  const int b1 = scal[0];
  const int before = scal[1];
  __syncthreads();
  for (int i = tid; i < 1024; i += 256) hist[i] = 0u;
  __syncthreads();
  // pass 2: refine next 10 bits within bin b1
  for (int i = tid; i < NANCH; i += 256) {
    unsigned u = keybits(obj[i]);
    if ((int)(u >> 22) == b1) atomicAdd(&hist[(u >> 12) & 1023u], 1u);
  }
  __syncthreads();
  find_bin(hist, coarse, PRE_K - before, tid, scal);
  const unsigned Tbits = ((unsigned)b1 << 22) | ((unsigned)scal[0] << 12);
  __syncthreads();
  // gather candidates (>=600 guaranteed, ~600 expected)
  for (int i = tid; i < NANCH; i += 256) {
    unsigned u = keybits(obj[i]);
    if (u >= Tbits) {
      int p = atomicAdd(&scal[2], 1);
      if (p < 1024)
        keys[p] = ((unsigned long long)u << 32) | (unsigned long long)(~(unsigned)i);
    }
  }
  __syncthreads();
  const int cnt = scal[2];
  for (int p = tid; p < 1024; p += 256) if (p >= cnt) keys[p] = 0ull;
  // bitonic sort descending (key: logit bits major, ~idx minor -> ties by lower idx)
  for (unsigned k = 2; k <= 1024; k <<= 1) {
    for (unsigned j = k >> 1; j > 0; j >>= 1) {
      __syncthreads();
      for (unsigned idx = tid; idx < 1024; idx += 256) {
        unsigned partner = idx ^ j;
        if (partner > idx) {
          unsigned long long a = keys[idx], c = keys[partner];
          bool up = ((idx & k) == 0);
          if (up ? (a < c) : (a > c)) { keys[idx] = c; keys[partner] = a; }
        }
      }
    }
  }
  __syncthreads();
  // decode top-600 boxes
  for (int t = tid; t < PRE_K; t += 256) {
    unsigned long long kv = keys[t];
    unsigned u  = (unsigned)(kv >> 32);
    unsigned i2 = ~((unsigned)kv);
    unsigned ub = (u & 0x80000000u) ? (u & 0x7fffffffu) : ~u;
    float logit = __uint_as_float(ub);
    float score = 1.f / (1.f + expf(-logit));
    int li = (int)(i2 / 7u);
    int a  = (int)(i2 - (unsigned)li * 7u);
    float alen = (float)(a + 1 + (a > 4 ? a - 4 : 0));
    const float* rp = out + REG_OFF + ((size_t)b * NANCH + i2) * 2;
    float tc = rp[0];
    float tw = fminf(fmaxf(rp[1], -10.f), 10.f);
    float cc = (float)li + 0.5f + tc * alen;
    float ww = alen * expf(tw);
    float s0 = cc - 0.5f * ww;
    float e0 = cc + 0.5f * ww;
    s0 = fminf(fmaxf(s0, 0.f), (float)LF);
    e0 = fminf(fmaxf(e0, 0.f), (float)LF);
    e0 = fminf(fmaxf(e0, s0 + 1e-3f), (float)LF);
    s0 = fmaxf(fminf(s0, e0 - 1e-3f), 0.f);
    bs[t] = s0; be[t] = e0; bsc[t] = score;
    if (score >= 0.1f) atomicOr(&vwords[t >> 6], 1ull << (t & 63));
  }
  __syncthreads();
  // suppression masks: pool[j*10+w] = bits i>j with iou(i,j) > 0.5
  for (int widx = tid; widx < PRE_K * 10; widx += 256) {
    int j = widx / 10;
    int w = widx - j * 10;
    int base = w * 64;
    unsigned long long m = 0ull;
    if (base + 63 > j) {
      float sj = bs[j], ej = be[j];
      float wj = ej - sj;
      for (int bit = 0; bit < 64; ++bit) {
        int i3 = base + bit;
        if (i3 > j && i3 < PRE_K) {
          float inter = fmaxf(fminf(ej, be[i3]) - fmaxf(sj, bs[i3]), 0.f);
          float uni = wj + (be[i3] - bs[i3]) - inter;
          float iou = inter / fmaxf(uni, 1e-6f);
          if (iou > 0.5f) m |= (1ull << bit);
        }
      }
    }
    pool[widx] = m;
  }
  __syncthreads();
  // wave-serial greedy NMS + output (lane w<10 owns removal word w)
  if (wave == 0) {
    unsigned long long rem = 0ull;
    unsigned long long vw = (lane < 10) ? vwords[lane] : 0ull;
    unsigned long long mrow = (lane < 10) ? pool[lane] : 0ull;
    int kept = 0;
    for (int i3 = 0; i3 < PRE_K; ++i3) {
      unsigned long long mnext =
          (lane < 10 && (i3 + 1) < PRE_K) ? pool[(i3 + 1) * 10 + lane] : 0ull;
      unsigned long long avail = vw & ~rem;
      unsigned long long ow = __shfl(avail, i3 >> 6);
      if ((ow >> (i3 & 63)) & 1ull) {
        rem |= mrow;
        if (lane == 0) {
          out[PROPS_OFF + (size_t)b * 200 + 2 * kept]     = bs[i3];
          out[PROPS_OFF + (size_t)b * 200 + 2 * kept + 1] = be[i3];
          out[PSC_OFF + (size_t)b * 100 + kept] = bsc[i3];
          out[PM_OFF  + (size_t)b * 100 + kept] = 1.0f;
        }
        ++kept;
        if (kept >= POST_K) break;
      }
      mrow = mnext;
    }
    if (lane == 0) scal[3] = kept;
  }
  __syncthreads();
  const int kf = scal[3];
  for (int r = tid; r < POST_K; r += 256) {
    if (r >= kf) {
      out[PROPS_OFF + (size_t)b * 200 + 2 * r]     = 0.f;
      out[PROPS_OFF + (size_t)b * 200 + 2 * r + 1] = 0.f;
      out[PSC_OFF + (size_t)b * 100 + r] = 0.f;
      out[PM_OFF  + (size_t)b * 100 + r] = 0.f;
    }
  }
}

extern "C" void kernel_launch(void* const* d_in, const int* in_sizes, int n_in,
                              void* d_out, int out_size, void* d_ws, size_t ws_size,
                              hipStream_t stream) {
  const float* feat = (const float*)d_in[0];
  const float* cw   = (const float*)d_in[1];
  const float* cb   = (const float*)d_in[2];
  const float* ow   = (const float*)d_in[3];
  const float* obb  = (const float*)d_in[4];
  const float* rw   = (const float*)d_in[5];
  const float* rb   = (const float*)d_in[6];
  float* out = (float*)d_out;
  float* wt  = (float*)d_ws;   // 3 MB transposed conv weights

  hipLaunchKernelGGL(transpose_w_k, dim3(3072), dim3(256), 0, stream, cw, wt);
  hipLaunchKernelGGL(anchors_k, dim3(224), dim3(256), 0, stream, out);
  hipLaunchKernelGGL(conv_proj_k, dim3(256, 8), dim3(256), 0, stream,
                     feat, wt, cb, ow, obb, rw, rb, out);
  hipLaunchKernelGGL(propose_k, dim3(8), dim3(256), 0, stream, out);
}

// Round 6
// 2013.408 us; speedup vs baseline: 1.3653x; 1.2653x over previous
//
#include <hip/hip_runtime.h>

#define LF 8192
#define NB 8
#define NC 512
#define NA 7
#define NANCH 57344        // LF*NA
#define PRE_K 600
#define POST_K 100

// output layout (floats), concatenated in reference return order
#define OBJ_OFF   0
#define REG_OFF   458752
#define ANCH_OFF  1376256
#define PROPS_OFF 1490944
#define PSC_OFF   1492544
#define PM_OFF    1493344

// ---------------- weight transpose: conv_w[co][ci][k] -> wt[(ci*3+k)*512+co] ----
__global__ void transpose_w_k(const float* __restrict__ cw, float* __restrict__ wt) {
  int o = blockIdx.x * 256 + threadIdx.x;
  if (o >= 512 * 512 * 3) return;
  int co = o & 511;
  int r  = o >> 9;            // ci*3 + k
  int ci = r / 3;
  int k  = r - ci * 3;
  wt[o] = cw[((size_t)co * 512 + ci) * 3 + k];
}

// ---------------- anchors ------------------------------------------------------
__global__ void anchors_k(float* __restrict__ out) {
  int i = blockIdx.x * 256 + threadIdx.x;
  if (i >= NANCH) return;
  int l = i / 7, a = i - l * 7;
  float len = (float)(a + 1 + (a > 4 ? a - 4 : 0));   // {1,2,3,4,5,7,9}
  float c = (float)l + 0.5f;
  out[ANCH_OFF + 2 * (size_t)i]     = c - 0.5f * len;
  out[ANCH_OFF + 2 * (size_t)i + 1] = c + 0.5f * len;
}

// ---------------- fused conv1d + ReLU + obj/reg partial projection -------------
// grid (256 l-tiles, 2 co-halves, 8 b), block 256. Thread owns ONE c_out and a
// 32-l register tile: acc[32] fits in VGPRs (R5 evidence: 64 acc/thread forces
// AGPR shuttling, +60% VALU ops). Feat broadcast from double-buffered LDS;
// weights coalesced vector loads. obj/reg written via atomicAdd over a zeroed
// region (2 partial blocks per output).
// CAP LAW (R1/R3/R4): __launch_bounds__(256, w) caps VGPRs at 256/w — never
// pass a second arg >= 2 here.
__global__ __launch_bounds__(256) void conv_proj_k(
    const float* __restrict__ feat, const float* __restrict__ wt,
    const float* __restrict__ cbias, const float* __restrict__ obj_w,
    const float* __restrict__ obj_b, const float* __restrict__ reg_w,
    const float* __restrict__ reg_b, float* __restrict__ out)
{
  // union: sf double buffer (2*32*36=2304 floats) / epilogue bufp (128*33=4224)
  __shared__ __align__(16) float smem[4224];
  const int tid = threadIdx.x;
  const int l0  = blockIdx.x * 32;
  const int coh = blockIdx.y;          // co half: 0 or 1
  const int b   = blockIdx.z;
  const int co  = coh * 256 + tid;

  float acc[32];
  {
    float b0 = cbias[co];
    #pragma unroll
    for (int j = 0; j < 32; ++j) acc[j] = b0;
  }

  const float* fb = feat + ((size_t)b * 512) * LF;

  // ---- preload chunk cb=0 into buffer 0 ----
  #pragma unroll
  for (int t = 0; t < 5; ++t) {
    int idx = tid + t * 256;
    if (idx < 1088) {
      int r = idx / 34, c = idx - r * 34;
      int gl = l0 - 1 + c;
      float v = 0.f;
      if (gl >= 0 && gl < LF) v = fb[(size_t)r * LF + gl];
      smem[r * 36 + c] = v;
    }
  }
  __syncthreads();

  int p = 0;
  for (int cb = 0; cb < 512; cb += 32) {
    const bool more = (cb + 32 < 512);
    // issue next chunk's global loads (latency hidden behind 32-ci compute)
    float nst0 = 0.f, nst1 = 0.f, nst2 = 0.f, nst3 = 0.f, nst4 = 0.f;
    if (more) {
      #pragma unroll
      for (int t = 0; t < 5; ++t) {
        int idx = tid + t * 256;
        if (idx < 1088) {
          int r = idx / 34, c = idx - r * 34;
          int gl = l0 - 1 + c;
          float v = 0.f;
          if (gl >= 0 && gl < LF) v = fb[(size_t)(cb + 32 + r) * LF + gl];
          if (t == 0) nst0 = v; else if (t == 1) nst1 = v;
          else if (t == 2) nst2 = v; else if (t == 3) nst3 = v; else nst4 = v;
        }
      }
    }
    const float* sbase = smem + p * 1152;   // 32*36
    for (int ci = 0; ci < 32; ++ci) {
      const float* wp = wt + (size_t)(cb + ci) * 1536 + co;
      float w0 = wp[0], w1 = wp[512], w2 = wp[1024];
      const float4* fr = (const float4*)(sbase + ci * 36);  // wave-uniform -> broadcast
      float4 cur = fr[0];
      #pragma unroll
      for (int g = 0; g < 8; ++g) {
        float4 nxt = fr[g + 1];
        int l = 4 * g;
        acc[l]     = fmaf(w0, cur.x, fmaf(w1, cur.y, fmaf(w2, cur.z, acc[l])));
        acc[l + 1] = fmaf(w0, cur.y, fmaf(w1, cur.z, fmaf(w2, cur.w, acc[l + 1])));
        acc[l + 2] = fmaf(w0, cur.z, fmaf(w1, cur.w, fmaf(w2, nxt.x, acc[l + 2])));
        acc[l + 3] = fmaf(w0, cur.w, fmaf(w1, nxt.x, fmaf(w2, nxt.y, acc[l + 3])));
        cur = nxt;
      }
    }
    if (more) {
      float* dbase = smem + (p ^ 1) * 1152;
      #pragma unroll
      for (int t = 0; t < 5; ++t) {
        int idx = tid + t * 256;
        if (idx < 1088) {
          int r = idx / 34, c = idx - r * 34;
          float v = (t == 0) ? nst0 : (t == 1) ? nst1 : (t == 2) ? nst2
                  : (t == 3) ? nst3 : nst4;
          dbase[r * 36 + c] = v;
        }
      }
    }
    __syncthreads();
    p ^= 1;
  }

  // ---- partial projection epilogue over this block's 256 channels ----
  float* bufp = smem;                 // [128][33]
  const int sg = tid >> 5;            // subgroup 0..7: rows r = 3*sg + q
  const int ll = tid & 31;            // l within tile
  const int r0 = sg * 3;
  int rc0 = r0     < 21 ? r0     : 20;
  int rc1 = r0 + 1 < 21 ? r0 + 1 : 20;
  int rc2 = r0 + 2 < 21 ? r0 + 2 : 20;
  const float* wr0 = ((rc0 < 7) ? (obj_w + (size_t)rc0 * 512) : (reg_w + (size_t)(rc0 - 7) * 512)) + coh * 256;
  const float* wr1 = ((rc1 < 7) ? (obj_w + (size_t)rc1 * 512) : (reg_w + (size_t)(rc1 - 7) * 512)) + coh * 256;
  const float* wr2 = ((rc2 < 7) ? (obj_w + (size_t)rc2 * 512) : (reg_w + (size_t)(rc2 - 7) * 512)) + coh * 256;
  float pacc0 = 0.f, pacc1 = 0.f, pacc2 = 0.f;

  #pragma unroll
  for (int qh = 0; qh < 2; ++qh) {
    __syncthreads();
    if ((tid >> 7) == qh) {
      int row = tid & 127;
      #pragma unroll
      for (int j = 0; j < 32; ++j) bufp[row * 33 + j] = fmaxf(acc[j], 0.f);
    }
    __syncthreads();
    const float* w0p = wr0 + qh * 128;
    const float* w1p = wr1 + qh * 128;
    const float* w2p = wr2 + qh * 128;
    for (int c = 0; c < 128; ++c) {
      float hv = bufp[c * 33 + ll];
      pacc0 = fmaf(w0p[c], hv, pacc0);
      pacc1 = fmaf(w1p[c], hv, pacc1);
      pacc2 = fmaf(w2p[c], hv, pacc2);
    }
  }

  const size_t ob = (size_t)b * NANCH;
  const int l = l0 + ll;
  {
    int r = r0;
    if (r < 21) {
      float v = pacc0 + ((coh == 0) ? ((r < 7) ? obj_b[r] : reg_b[r - 7]) : 0.f);
      if (r < 7) atomicAdd(&out[OBJ_OFF + ob + (size_t)l * 7 + r], v);
      else { int rr = r - 7; atomicAdd(&out[REG_OFF + (ob + (size_t)l * 7 + (rr >> 1)) * 2 + (rr & 1)], v); }
    }
    r = r0 + 1;
    if (r < 21) {
      float v = pacc1 + ((coh == 0) ? ((r < 7) ? obj_b[r] : reg_b[r - 7]) : 0.f);
      if (r < 7) atomicAdd(&out[OBJ_OFF + ob + (size_t)l * 7 + r], v);
      else { int rr = r - 7; atomicAdd(&out[REG_OFF + (ob + (size_t)l * 7 + (rr >> 1)) * 2 + (rr & 1)], v); }
    }
    r = r0 + 2;
    if (r < 21) {
      float v = pacc2 + ((coh == 0) ? ((r < 7) ? obj_b[r] : reg_b[r - 7]) : 0.f);
      if (r < 7) atomicAdd(&out[OBJ_OFF + ob + (size_t)l * 7 + r], v);
      else { int rr = r - 7; atomicAdd(&out[REG_OFF + (ob + (size_t)l * 7 + (rr >> 1)) * 2 + (rr & 1)], v); }
    }
  }
}

// ---------------- helper: locate bin containing rank-K from top ----------------
__device__ __forceinline__ void find_bin(unsigned* hist, unsigned* coarse,
                                         int K, int tid, int* res) {
  unsigned s4 = hist[4 * tid] + hist[4 * tid + 1] + hist[4 * tid + 2] + hist[4 * tid + 3];
  coarse[tid] = s4;
  __syncthreads();
  for (int off = 1; off < 256; off <<= 1) {
    unsigned v = coarse[tid];
    unsigned add = (tid + off < 256) ? coarse[tid + off] : 0u;
    __syncthreads();
    coarse[tid] = v + add;
    __syncthreads();
  }
  unsigned sfx  = coarse[tid];
  unsigned sfx1 = (tid < 255) ? coarse[tid + 1] : 0u;
  if (sfx >= (unsigned)K && sfx1 < (unsigned)K) {
    unsigned above = sfx1;
    int bin = 4 * tid;
    for (int bb = 4 * tid + 3; bb >= 4 * tid; --bb) {
      unsigned c = hist[bb];
      if (above + c >= (unsigned)K) { bin = bb; break; }
      above += c;
    }
    res[0] = bin;
    res[1] = (int)above;
  }
  __syncthreads();
}

// monotone sortable bits of a float logit (total order == value order)
__device__ __forceinline__ unsigned keybits(float x) {
  unsigned u = __float_as_uint(x);
  return (u & 0x80000000u) ? ~u : (u | 0x80000000u);
}

// ---------------- per-batch top-600 -> NMS -> top-100 --------------------------
__global__ __launch_bounds__(256) void propose_k(float* __restrict__ out) {
  const int b = blockIdx.x;
  const int tid = threadIdx.x;
  const int lane = tid & 63;
  const int wave = tid >> 6;

  __shared__ unsigned long long pool[PRE_K * 10];  // 48 KB; first 1024 = sort keys
  __shared__ unsigned int hist[1024];
  __shared__ unsigned int coarse[256];
  __shared__ float bs[PRE_K], be[PRE_K], bsc[PRE_K];
  __shared__ unsigned long long vwords[10];
  __shared__ int scal[4];   // 0: bin, 1: before, 2: cand cnt, 3: kept

  unsigned long long* keys = pool;
  const float* obj = out + OBJ_OFF + (size_t)b * NANCH;

  for (int i = tid; i < 1024; i += 256) hist[i] = 0u;
  if (tid < 10) vwords[tid] = 0ull;
  if (tid == 0) scal[2] = 0;
  __syncthreads();

  // pass 1: histogram on sortable logit bits [31:22]
  for (int i = tid; i < NANCH; i += 256) {
    unsigned u = keybits(obj[i]);
    atomicAdd(&hist[u >> 22], 1u);
  }
  __syncthreads();
  find_bin(hist, coarse, PRE_K, tid, scal);
  const int b1 = scal[0];
  const int before = scal[1];
  __syncthreads();
  for (int i = tid; i < 1024; i += 256) hist[i] = 0u;
  __syncthreads();
  // pass 2: refine next 10 bits within bin b1
  for (int i = tid; i < NANCH; i += 256) {
    unsigned u = keybits(obj[i]);
    if ((int)(u >> 22) == b1) atomicAdd(&hist[(u >> 12) & 1023u], 1u);
  }
  __syncthreads();
  find_bin(hist, coarse, PRE_K - before, tid, scal);
  const unsigned Tbits = ((unsigned)b1 << 22) | ((unsigned)scal[0] << 12);
  __syncthreads();
  // gather candidates (>=600 guaranteed, ~600 expected)
  for (int i = tid; i < NANCH; i += 256) {
    unsigned u = keybits(obj[i]);
    if (u >= Tbits) {
      int p = atomicAdd(&scal[2], 1);
      if (p < 1024)
        keys[p] = ((unsigned long long)u << 32) | (unsigned long long)(~(unsigned)i);
    }
  }
  __syncthreads();
  const int cnt = scal[2];
  for (int p = tid; p < 1024; p += 256) if (p >= cnt) keys[p] = 0ull;
  // bitonic sort descending (key: logit bits major, ~idx minor -> ties by lower idx)
  for (unsigned k = 2; k <= 1024; k <<= 1) {
    for (unsigned j = k >> 1; j > 0; j >>= 1) {
      __syncthreads();
      for (unsigned idx = tid; idx < 1024; idx += 256) {
        unsigned partner = idx ^ j;
        if (partner > idx) {
          unsigned long long a = keys[idx], c = keys[partner];
          bool up = ((idx & k) == 0);
          if (up ? (a < c) : (a > c)) { keys[idx] = c; keys[partner] = a; }
        }
      }
    }
  }
  __syncthreads();
  // decode top-600 boxes
  for (int t = tid; t < PRE_K; t += 256) {
    unsigned long long kv = keys[t];
    unsigned u  = (unsigned)(kv >> 32);
    unsigned i2 = ~((unsigned)kv);
    unsigned ub = (u & 0x80000000u) ? (u & 0x7fffffffu) : ~u;
    float logit = __uint_as_float(ub);
    float score = 1.f / (1.f + expf(-logit));
    int li = (int)(i2 / 7u);
    int a  = (int)(i2 - (unsigned)li * 7u);
    float alen = (float)(a + 1 + (a > 4 ? a - 4 : 0));
    const float* rp = out + REG_OFF + ((size_t)b * NANCH + i2) * 2;
    float tc = rp[0];
    float tw = fminf(fmaxf(rp[1], -10.f), 10.f);
    float cc = (float)li + 0.5f + tc * alen;
    float ww = alen * expf(tw);
    float s0 = cc - 0.5f * ww;
    float e0 = cc + 0.5f * ww;
    s0 = fminf(fmaxf(s0, 0.f), (float)LF);
    e0 = fminf(fmaxf(e0, 0.f), (float)LF);
    e0 = fminf(fmaxf(e0, s0 + 1e-3f), (float)LF);
    s0 = fmaxf(fminf(s0, e0 - 1e-3f), 0.f);
    bs[t] = s0; be[t] = e0; bsc[t] = score;
    if (score >= 0.1f) atomicOr(&vwords[t >> 6], 1ull << (t & 63));
  }
  __syncthreads();
  // suppression masks: pool[j*10+w] = bits i>j with iou(i,j) > 0.5
  for (int widx = tid; widx < PRE_K * 10; widx += 256) {
    int j = widx / 10;
    int w = widx - j * 10;
    int base = w * 64;
    unsigned long long m = 0ull;
    if (base + 63 > j) {
      float sj = bs[j], ej = be[j];
      float wj = ej - sj;
      for (int bit = 0; bit < 64; ++bit) {
        int i3 = base + bit;
        if (i3 > j && i3 < PRE_K) {
          float inter = fmaxf(fminf(ej, be[i3]) - fmaxf(sj, bs[i3]), 0.f);
          float uni = wj + (be[i3] - bs[i3]) - inter;
          float iou = inter / fmaxf(uni, 1e-6f);
          if (iou > 0.5f) m |= (1ull << bit);
        }
      }
    }
    pool[widx] = m;
  }
  __syncthreads();
  // wave-serial greedy NMS + output (lane w<10 owns removal word w)
  if (wave == 0) {
    unsigned long long rem = 0ull;
    unsigned long long vw = (lane < 10) ? vwords[lane] : 0ull;
    unsigned long long mrow = (lane < 10) ? pool[lane] : 0ull;
    int kept = 0;
    for (int i3 = 0; i3 < PRE_K; ++i3) {
      unsigned long long mnext =
          (lane < 10 && (i3 + 1) < PRE_K) ? pool[(i3 + 1) * 10 + lane] : 0ull;
      unsigned long long avail = vw & ~rem;
      unsigned long long ow = __shfl(avail, i3 >> 6);
      if ((ow >> (i3 & 63)) & 1ull) {
        rem |= mrow;
        if (lane == 0) {
          out[PROPS_OFF + (size_t)b * 200 + 2 * kept]     = bs[i3];
          out[PROPS_OFF + (size_t)b * 200 + 2 * kept + 1] = be[i3];
          out[PSC_OFF + (size_t)b * 100 + kept] = bsc[i3];
          out[PM_OFF  + (size_t)b * 100 + kept] = 1.0f;
        }
        ++kept;
        if (kept >= POST_K) break;
      }
      mrow = mnext;
    }
    if (lane == 0) scal[3] = kept;
  }
  __syncthreads();
  const int kf = scal[3];
  for (int r = tid; r < POST_K; r += 256) {
    if (r >= kf) {
      out[PROPS_OFF + (size_t)b * 200 + 2 * r]     = 0.f;
      out[PROPS_OFF + (size_t)b * 200 + 2 * r + 1] = 0.f;
      out[PSC_OFF + (size_t)b * 100 + r] = 0.f;
      out[PM_OFF  + (size_t)b * 100 + r] = 0.f;
    }
  }
}

extern "C" void kernel_launch(void* const* d_in, const int* in_sizes, int n_in,
                              void* d_out, int out_size, void* d_ws, size_t ws_size,
                              hipStream_t stream) {
  const float* feat = (const float*)d_in[0];
  const float* cw   = (const float*)d_in[1];
  const float* cb   = (const float*)d_in[2];
  const float* ow   = (const float*)d_in[3];
  const float* obb  = (const float*)d_in[4];
  const float* rw   = (const float*)d_in[5];
  const float* rb   = (const float*)d_in[6];
  float* out = (float*)d_out;
  float* wt  = (float*)d_ws;   // 3 MB transposed conv weights

  // zero obj+reg region (atomicAdd partial-sum target)
  hipMemsetAsync(out, 0, (size_t)REG_OFF * 4 + (size_t)(ANCH_OFF - REG_OFF) * 4, stream);
  hipLaunchKernelGGL(transpose_w_k, dim3(3072), dim3(256), 0, stream, cw, wt);
  hipLaunchKernelGGL(anchors_k, dim3(224), dim3(256), 0, stream, out);
  hipLaunchKernelGGL(conv_proj_k, dim3(256, 2, 8), dim3(256), 0, stream,
                     feat, wt, cb, ow, obb, rw, rb, out);
  hipLaunchKernelGGL(propose_k, dim3(8), dim3(256), 0, stream, out);
}

// Round 7
// 961.435 us; speedup vs baseline: 2.8591x; 2.0942x over previous
//
#include <hip/hip_runtime.h>

#define LF 8192
#define NB 8
#define NC 512
#define NA 7
#define NANCH 57344        // LF*NA
#define PRE_K 600
#define POST_K 100

// output layout (floats), concatenated in reference return order
#define OBJ_OFF   0
#define REG_OFF   458752
#define ANCH_OFF  1376256
#define PROPS_OFF 1490944
#define PSC_OFF   1492544
#define PM_OFF    1493344

typedef __attribute__((ext_vector_type(8))) short bf16x8;
typedef __attribute__((ext_vector_type(4))) float f32x4;

__device__ __forceinline__ unsigned short f2bf(float f) {   // RNE float->bf16
  unsigned u = __float_as_uint(f);
  u += 0x7fff + ((u >> 16) & 1);
  return (unsigned short)(u >> 16);
}
__device__ __forceinline__ float bf2f(unsigned short h) {
  return __uint_as_float(((unsigned)h) << 16);
}

// ---- weight prep: conv_w[co][ci][tap] -> split-bf16, MFMA-A-fragment order ----
// layout: [cc=cob*16+chunk (64)][tap 3][cotl 8][split 2][lane 64][j 8]
// frag semantics: co = cob*128 + cotl*16 + (lane&15); ci = chunk*32 + (lane>>4)*8 + j
__global__ void prep_w_k(const float* __restrict__ cw, unsigned short* __restrict__ wf) {
  int o = blockIdx.x * 256 + threadIdx.x;      // 786432 items (both splits per item)
  if (o >= 786432) return;
  int j    = o & 7;
  int lane = (o >> 3) & 63;
  int cotl = (o >> 9) & 7;
  int rem  = o >> 12;                          // cc*3 + tap, 0..191
  int tap  = rem % 3;
  int cc   = rem / 3;                          // cob*16 + chunk
  int co = (cc >> 4) * 128 + cotl * 16 + (lane & 15);
  int ci = (cc & 15) * 32 + (lane >> 4) * 8 + j;
  float w = cw[((size_t)co * 512 + ci) * 3 + tap];
  unsigned short hi = f2bf(w);
  unsigned short lo = f2bf(w - bf2f(hi));
  size_t base = ((((size_t)rem * 8 + cotl) * 2) * 64 + lane) * 8 + j;
  wf[base] = hi;
  wf[base + 512] = lo;                         // split stride = 64*8
}

// ---------------- anchors ------------------------------------------------------
__global__ void anchors_k(float* __restrict__ out) {
  int i = blockIdx.x * 256 + threadIdx.x;
  if (i >= NANCH) return;
  int l = i / 7, a = i - l * 7;
  float len = (float)(a + 1 + (a > 4 ? a - 4 : 0));   // {1,2,3,4,5,7,9}
  float c = (float)l + 0.5f;
  out[ANCH_OFF + 2 * (size_t)i]     = c - 0.5f * len;
  out[ANCH_OFF + 2 * (size_t)i + 1] = c + 0.5f * len;
}

// ---- split-bf16 MFMA conv + ReLU + projection ---------------------------------
// grid (64 l-tiles, 4 co-blocks, 8 b), block 256 (4 waves as 2x2).
// C[m=co 128][n=l 128]; K = 512 ci in 16 chunks of 32; 3 taps = 3 A-matrices,
// B row-shifted. 3 split terms: Ahi*Bhi + Ahi*Blo + Alo*Bhi (fp32 accum).
// A-frags direct from global (pre-fragmented, L2); feat split+transposed into
// LDS [row 130][ci 40] bf16. CAP LAW: no second __launch_bounds__ arg (R3/R4).
__global__ __launch_bounds__(256) void conv_proj_k(
    const float* __restrict__ feat, const unsigned short* __restrict__ wfrag,
    const float* __restrict__ cbias, const float* __restrict__ obj_w,
    const float* __restrict__ obj_b, const float* __restrict__ reg_w,
    const float* __restrict__ reg_b, float* __restrict__ out)
{
  __shared__ __align__(16) char smem[33536];   // max(feat 20800, bufp 33280)
  unsigned short* fhi = (unsigned short*)smem;        // [130][40]
  unsigned short* flo = fhi + 130 * 40;
  float* bufp = (float*)smem;                         // [64][130]

  const int tid  = threadIdx.x;
  const int l0   = blockIdx.x * 128;
  const int cob  = blockIdx.y;
  const int b    = blockIdx.z;
  const int lane = tid & 63, wave = tid >> 6;
  const int wm = wave >> 1, wn = wave & 1;
  const int quad = lane >> 4, l15 = lane & 15;

  const float* fb = feat + (size_t)b * 512 * LF;
  const bf16x8* wf8 = (const bf16x8*)wfrag;

  f32x4 acc[4][4];
  #pragma unroll
  for (int mt = 0; mt < 4; ++mt)
    #pragma unroll
    for (int nt = 0; nt < 4; ++nt) acc[mt][nt] = (f32x4){0.f, 0.f, 0.f, 0.f};

  const int r8 = tid & 7, cp = (tid >> 3) & 15, set = tid >> 7;

  for (int chunk = 0; chunk < 16; ++chunk) {
    const int cb = chunk * 32;
    // phase A: rows 1..128 (l = l0..l0+127, always in range)
    #pragma unroll
    for (int p = 0; p < 8; ++p) {
      int row = p * 16 + set * 8 + r8;
      int l = l0 + row;
      float v0 = fb[(size_t)(cb + 2 * cp) * LF + l];
      float v1 = fb[(size_t)(cb + 2 * cp + 1) * LF + l];
      unsigned short h0 = f2bf(v0), h1 = f2bf(v1);
      unsigned short g0 = f2bf(v0 - bf2f(h0)), g1 = f2bf(v1 - bf2f(h1));
      int e = (row + 1) * 40 + 2 * cp;
      *(unsigned*)(fhi + e) = (unsigned)h0 | ((unsigned)h1 << 16);
      *(unsigned*)(flo + e) = (unsigned)g0 | ((unsigned)g1 << 16);
    }
    // phase B: rows 0 and 129 (may be out of range -> zero)
    if (tid < 32) {
      int rr = tid >> 4, c2 = tid & 15;
      int l = (rr == 0) ? (l0 - 1) : (l0 + 128);
      int row = rr * 129;
      bool ok = (l >= 0) && (l < LF);
      float v0 = ok ? fb[(size_t)(cb + 2 * c2) * LF + l] : 0.f;
      float v1 = ok ? fb[(size_t)(cb + 2 * c2 + 1) * LF + l] : 0.f;
      unsigned short h0 = f2bf(v0), h1 = f2bf(v1);
      unsigned short g0 = f2bf(v0 - bf2f(h0)), g1 = f2bf(v1 - bf2f(h1));
      int e = row * 40 + 2 * c2;
      *(unsigned*)(fhi + e) = (unsigned)h0 | ((unsigned)h1 << 16);
      *(unsigned*)(flo + e) = (unsigned)g0 | ((unsigned)g1 << 16);
    }
    __syncthreads();

    const int rem = (cob * 16 + chunk) * 3;
    #pragma unroll
    for (int tap = 0; tap < 3; ++tap) {
      bf16x8 Ah[4], Al[4], Bh[4], Bl[4];
      #pragma unroll
      for (int mt = 0; mt < 4; ++mt) {
        int fi = (((rem + tap) * 8 + wm * 4 + mt) * 2) * 64 + lane;
        Ah[mt] = wf8[fi];
        Al[mt] = wf8[fi + 64];
      }
      #pragma unroll
      for (int nt = 0; nt < 4; ++nt) {
        int row = wn * 64 + nt * 16 + l15 + tap;
        int e = row * 40 + quad * 8;
        Bh[nt] = *(const bf16x8*)(fhi + e);
        Bl[nt] = *(const bf16x8*)(flo + e);
      }
      #pragma unroll
      for (int mt = 0; mt < 4; ++mt)
        #pragma unroll
        for (int nt = 0; nt < 4; ++nt) {
          acc[mt][nt] = __builtin_amdgcn_mfma_f32_16x16x32_bf16(Ah[mt], Bh[nt], acc[mt][nt], 0, 0, 0);
          acc[mt][nt] = __builtin_amdgcn_mfma_f32_16x16x32_bf16(Ah[mt], Bl[nt], acc[mt][nt], 0, 0, 0);
          acc[mt][nt] = __builtin_amdgcn_mfma_f32_16x16x32_bf16(Al[mt], Bh[nt], acc[mt][nt], 0, 0, 0);
        }
    }
    __syncthreads();
  }

  // ---- epilogue: bias + relu -> LDS half-tiles -> 21-row projection -----------
  const int sg = tid >> 5;           // 0..7 -> rows 3sg..3sg+2
  const int ll = tid & 31;
  int rc0 = 3 * sg     < 21 ? 3 * sg     : 20;
  int rc1 = 3 * sg + 1 < 21 ? 3 * sg + 1 : 20;
  int rc2 = 3 * sg + 2 < 21 ? 3 * sg + 2 : 20;
  const float* wr0 = (rc0 < 7) ? (obj_w + (size_t)rc0 * 512) : (reg_w + (size_t)(rc0 - 7) * 512);
  const float* wr1 = (rc1 < 7) ? (obj_w + (size_t)rc1 * 512) : (reg_w + (size_t)(rc1 - 7) * 512);
  const float* wr2 = (rc2 < 7) ? (obj_w + (size_t)rc2 * 512) : (reg_w + (size_t)(rc2 - 7) * 512);
  float pacc[3][4];
  #pragma unroll
  for (int q = 0; q < 3; ++q)
    #pragma unroll
    for (int m = 0; m < 4; ++m) pacc[q][m] = 0.f;

  #pragma unroll
  for (int h = 0; h < 2; ++h) {
    __syncthreads();
    if (wm == h) {
      #pragma unroll
      for (int mt = 0; mt < 4; ++mt) {
        f32x4 bv = *(const f32x4*)(cbias + cob * 128 + h * 64 + mt * 16 + quad * 4);
        #pragma unroll
        for (int nt = 0; nt < 4; ++nt) {
          int col = wn * 64 + nt * 16 + l15;
          #pragma unroll
          for (int r = 0; r < 4; ++r)
            bufp[(mt * 16 + quad * 4 + r) * 130 + col] = fmaxf(acc[mt][nt][r] + bv[r], 0.f);
        }
      }
    }
    __syncthreads();
    for (int c = 0; c < 64; ++c) {
      int cg = cob * 128 + h * 64 + c;
      float w0 = wr0[cg], w1 = wr1[cg], w2 = wr2[cg];
      #pragma unroll
      for (int m = 0; m < 4; ++m) {
        float hv = bufp[c * 130 + ll + 32 * m];
        pacc[0][m] = fmaf(w0, hv, pacc[0][m]);
        pacc[1][m] = fmaf(w1, hv, pacc[1][m]);
        pacc[2][m] = fmaf(w2, hv, pacc[2][m]);
      }
    }
  }

  const size_t ob = (size_t)b * NANCH;
  #pragma unroll
  for (int q = 0; q < 3; ++q) {
    int r = 3 * sg + q;
    if (r < 21) {
      #pragma unroll
      for (int m = 0; m < 4; ++m) {
        int l = l0 + ll + 32 * m;
        float v = pacc[q][m] + ((cob == 0) ? ((r < 7) ? obj_b[r] : reg_b[r - 7]) : 0.f);
        if (r < 7) atomicAdd(&out[OBJ_OFF + ob + (size_t)l * 7 + r], v);
        else { int rr = r - 7; atomicAdd(&out[REG_OFF + (ob + (size_t)l * 7 + (rr >> 1)) * 2 + (rr & 1)], v); }
      }
    }
  }
}

// ---------------- helper: locate bin containing rank-K from top ----------------
__device__ __forceinline__ void find_bin(unsigned* hist, unsigned* coarse,
                                         int K, int tid, int* res) {
  unsigned s4 = hist[4 * tid] + hist[4 * tid + 1] + hist[4 * tid + 2] + hist[4 * tid + 3];
  coarse[tid] = s4;
  __syncthreads();
  for (int off = 1; off < 256; off <<= 1) {
    unsigned v = coarse[tid];
    unsigned add = (tid + off < 256) ? coarse[tid + off] : 0u;
    __syncthreads();
    coarse[tid] = v + add;
    __syncthreads();
  }
  unsigned sfx  = coarse[tid];
  unsigned sfx1 = (tid < 255) ? coarse[tid + 1] : 0u;
  if (sfx >= (unsigned)K && sfx1 < (unsigned)K) {
    unsigned above = sfx1;
    int bin = 4 * tid;
    for (int bb = 4 * tid + 3; bb >= 4 * tid; --bb) {
      unsigned c = hist[bb];
      if (above + c >= (unsigned)K) { bin = bb; break; }
      above += c;
    }
    res[0] = bin;
    res[1] = (int)above;
  }
  __syncthreads();
}

// monotone sortable bits of a float logit (total order == value order)
__device__ __forceinline__ unsigned keybits(float x) {
  unsigned u = __float_as_uint(x);
  return (u & 0x80000000u) ? ~u : (u | 0x80000000u);
}

// ---------------- per-batch top-600 -> NMS -> top-100 --------------------------
__global__ __launch_bounds__(256) void propose_k(float* __restrict__ out) {
  const int b = blockIdx.x;
  const int tid = threadIdx.x;
  const int lane = tid & 63;
  const int wave = tid >> 6;

  __shared__ unsigned long long pool[PRE_K * 10];  // 48 KB; first 1024 = sort keys
  __shared__ unsigned int hist[1024];
  __shared__ unsigned int coarse[256];
  __shared__ float bs[PRE_K], be[PRE_K], bsc[PRE_K];
  __shared__ unsigned long long vwords[10];
  __shared__ int scal[4];

  unsigned long long* keys = pool;
  const float* obj = out + OBJ_OFF + (size_t)b * NANCH;

  for (int i = tid; i < 1024; i += 256) hist[i] = 0u;
  if (tid < 10) vwords[tid] = 0ull;
  if (tid == 0) scal[2] = 0;
  __syncthreads();

  for (int i = tid; i < NANCH; i += 256) {
    unsigned u = keybits(obj[i]);
    atomicAdd(&hist[u >> 22], 1u);
  }
  __syncthreads();
  find_bin(hist, coarse, PRE_K, tid, scal);
  const int b1 = scal[0];
  const int before = scal[1];
  __syncthreads();
  for (int i = tid; i < 1024; i += 256) hist[i] = 0u;
  __syncthreads();
  for (int i = tid; i < NANCH; i += 256) {
    unsigned u = keybits(obj[i]);
    if ((int)(u >> 22) == b1) atomicAdd(&hist[(u >> 12) & 1023u], 1u);
  }
  __syncthreads();
  find_bin(hist, coarse, PRE_K - before, tid, scal);
  const unsigned Tbits = ((unsigned)b1 << 22) | ((unsigned)scal[0] << 12);
  __syncthreads();
  for (int i = tid; i < NANCH; i += 256) {
    unsigned u = keybits(obj[i]);
    if (u >= Tbits) {
      int p = atomicAdd(&scal[2], 1);
      if (p < 1024)
        keys[p] = ((unsigned long long)u << 32) | (unsigned long long)(~(unsigned)i);
    }
  }
  __syncthreads();
  const int cnt = scal[2];
  for (int p = tid; p < 1024; p += 256) if (p >= cnt) keys[p] = 0ull;
  for (unsigned k = 2; k <= 1024; k <<= 1) {
    for (unsigned j = k >> 1; j > 0; j >>= 1) {
      __syncthreads();
      for (unsigned idx = tid; idx < 1024; idx += 256) {
        unsigned partner = idx ^ j;
        if (partner > idx) {
          unsigned long long a = keys[idx], c = keys[partner];
          bool up = ((idx & k) == 0);
          if (up ? (a < c) : (a > c)) { keys[idx] = c; keys[partner] = a; }
        }
      }
    }
  }
  __syncthreads();
  for (int t = tid; t < PRE_K; t += 256) {
    unsigned long long kv = keys[t];
    unsigned u  = (unsigned)(kv >> 32);
    unsigned i2 = ~((unsigned)kv);
    unsigned ub = (u & 0x80000000u) ? (u & 0x7fffffffu) : ~u;
    float logit = __uint_as_float(ub);
    float score = 1.f / (1.f + expf(-logit));
    int li = (int)(i2 / 7u);
    int a  = (int)(i2 - (unsigned)li * 7u);
    float alen = (float)(a + 1 + (a > 4 ? a - 4 : 0));
    const float* rp = out + REG_OFF + ((size_t)b * NANCH + i2) * 2;
    float tc = rp[0];
    float tw = fminf(fmaxf(rp[1], -10.f), 10.f);
    float cc = (float)li + 0.5f + tc * alen;
    float ww = alen * expf(tw);
    float s0 = cc - 0.5f * ww;
    float e0 = cc + 0.5f * ww;
    s0 = fminf(fmaxf(s0, 0.f), (float)LF);
    e0 = fminf(fmaxf(e0, 0.f), (float)LF);
    e0 = fminf(fmaxf(e0, s0 + 1e-3f), (float)LF);
    s0 = fmaxf(fminf(s0, e0 - 1e-3f), 0.f);
    bs[t] = s0; be[t] = e0; bsc[t] = score;
    if (score >= 0.1f) atomicOr(&vwords[t >> 6], 1ull << (t & 63));
  }
  __syncthreads();
  for (int widx = tid; widx < PRE_K * 10; widx += 256) {
    int j = widx / 10;
    int w = widx - j * 10;
    int base = w * 64;
    unsigned long long m = 0ull;
    if (base + 63 > j) {
      float sj = bs[j], ej = be[j];
      float wj = ej - sj;
      for (int bit = 0; bit < 64; ++bit) {
        int i3 = base + bit;
        if (i3 > j && i3 < PRE_K) {
          float inter = fmaxf(fminf(ej, be[i3]) - fmaxf(sj, bs[i3]), 0.f);
          float uni = wj + (be[i3] - bs[i3]) - inter;
          float iou = inter / fmaxf(uni, 1e-6f);
          if (iou > 0.5f) m |= (1ull << bit);
        }
      }
    }
    pool[widx] = m;
  }
  __syncthreads();
  if (wave == 0) {
    unsigned long long rem = 0ull;
    unsigned long long vw = (lane < 10) ? vwords[lane] : 0ull;
    unsigned long long mrow = (lane < 10) ? pool[lane] : 0ull;
    int kept = 0;
    for (int i3 = 0; i3 < PRE_K; ++i3) {
      unsigned long long mnext =
          (lane < 10 && (i3 + 1) < PRE_K) ? pool[(i3 + 1) * 10 + lane] : 0ull;
      unsigned long long avail = vw & ~rem;
      unsigned long long ow = __shfl(avail, i3 >> 6);
      if ((ow >> (i3 & 63)) & 1ull) {
        rem |= mrow;
        if (lane == 0) {
          out[PROPS_OFF + (size_t)b * 200 + 2 * kept]     = bs[i3];
          out[PROPS_OFF + (size_t)b * 200 + 2 * kept + 1] = be[i3];
          out[PSC_OFF + (size_t)b * 100 + kept] = bsc[i3];
          out[PM_OFF  + (size_t)b * 100 + kept] = 1.0f;
        }
        ++kept;
        if (kept >= POST_K) break;
      }
      mrow = mnext;
    }
    if (lane == 0) scal[3] = kept;
  }
  __syncthreads();
  const int kf = scal[3];
  for (int r = tid; r < POST_K; r += 256) {
    if (r >= kf) {
      out[PROPS_OFF + (size_t)b * 200 + 2 * r]     = 0.f;
      out[PROPS_OFF + (size_t)b * 200 + 2 * r + 1] = 0.f;
      out[PSC_OFF + (size_t)b * 100 + r] = 0.f;
      out[PM_OFF  + (size_t)b * 100 + r] = 0.f;
    }
  }
}

extern "C" void kernel_launch(void* const* d_in, const int* in_sizes, int n_in,
                              void* d_out, int out_size, void* d_ws, size_t ws_size,
                              hipStream_t stream) {
  const float* feat = (const float*)d_in[0];
  const float* cw   = (const float*)d_in[1];
  const float* cb   = (const float*)d_in[2];
  const float* ow   = (const float*)d_in[3];
  const float* obb  = (const float*)d_in[4];
  const float* rw   = (const float*)d_in[5];
  const float* rb   = (const float*)d_in[6];
  float* out = (float*)d_out;
  unsigned short* wf = (unsigned short*)d_ws;   // 3.14 MB prefragmented split-bf16 weights

  // zero obj+reg region (atomicAdd partial-sum target)
  hipMemsetAsync(out, 0, (size_t)(REG_OFF + (ANCH_OFF - REG_OFF)) * 4, stream);
  hipLaunchKernelGGL(prep_w_k, dim3(3072), dim3(256), 0, stream, cw, wf);
  hipLaunchKernelGGL(anchors_k, dim3(224), dim3(256), 0, stream, out);
  hipLaunchKernelGGL(conv_proj_k, dim3(64, 4, 8), dim3(256), 0, stream,
                     feat, wf, cb, ow, obb, rw, rb, out);
  hipLaunchKernelGGL(propose_k, dim3(8), dim3(256), 0, stream, out);
}